// Round 5
// baseline (254.253 us; speedup 1.0000x reference)
//
#include <hip/hip_runtime.h>

// AttentionFlow: B=8, N=50000, D=32, DEG=8, E=800000; segments = 8 consecutive edges.
//
// ONE EDGE PER LANE. Each lane reads its 4 operand rows (hc[vi], hc[vj], hu[vj],
// rel_emb[rel]; 32 floats each) as 8 float4s and accumulates the logit per-lane.
// Every gather instruction spans up to 64 distinct 128B lines (vs 8 in the old
// k*8+q layout) -> ~8x memory-level parallelism per wave. Segments align with
// 8-lane groups (idx_vi == e>>3), so softmax = shfl_xor(1,2,4) over width 8.
// Weights (ws/b/out_w) are staged in LDS (768B) and read as broadcasts.
// out_b is dropped: it adds a constant to every logit in a segment -> cancels
// in the segment softmax.

#define DDIM 32

__global__ __launch_bounds__(256, 8) void attn_flow_kernel(
    const float* __restrict__ node_attention,   // B*N
    const float* __restrict__ hidden_con,       // B*N*D
    const float* __restrict__ hidden_uncon,     // N*D
    const float* __restrict__ edges_y,          // E
    const float* __restrict__ rel_emb,          // R*D
    const float* __restrict__ ws,               // 4*D
    const float* __restrict__ bvec,             // D
    const float* __restrict__ out_w,            // D
    const int*   __restrict__ edges,            // E*6 (idx,vi,vj,rel,idx_vi,key)
    float* __restrict__ trans_attention,        // E
    float* __restrict__ new_node_attention,     // B*N
    long E_total, int N_nodes)
{
    __shared__ float lw[6 * DDIM];   // w0 w1 w2 w3 | b | out_w
    {
        const int t = threadIdx.x;
        if (t < 4 * DDIM)                    lw[t]       = ws[t];
        else if (t < 5 * DDIM)               lw[t]       = bvec[t - 4 * DDIM];
        else if (t < 6 * DDIM)               lw[t]       = out_w[t - 5 * DDIM];
    }
    __syncthreads();

    const long e = (long)blockIdx.x * 256 + threadIdx.x;   // this lane's edge
    if (e >= E_total) return;

    // headers: (idx, vi) from this edge's segment start; (vj, rel) per edge
    const long g = e >> 3;
    const int2 h = *(const int2*)(edges + g * 48);      // idx, vi (8 lanes share)
    const int2 p = *(const int2*)(edges + e * 6 + 2);   // vj, rel

    const long bc = (long)h.x * N_nodes;
    const float4* __restrict__ arow = (const float4*)(hidden_con  + (bc + h.y) * DDIM);
    const float4* __restrict__ crow = (const float4*)(hidden_con  + (bc + p.x) * DDIM);
    const float4* __restrict__ urow = (const float4*)(hidden_uncon + (long)p.x * DDIM);
    const float4* __restrict__ rrow = (const float4*)(rel_emb     + (long)p.y * DDIM);

    float logit = 0.f;
#pragma unroll
    for (int j = 0; j < DDIM / 4; ++j) {
        const float4 a = arow[j];
        const float4 c = crow[j];
        const float4 u = urow[j];
        const float4 r = rrow[j];
        const float4 w0 = ((const float4*)(lw           ))[j];
        const float4 w1 = ((const float4*)(lw +   DDIM ))[j];
        const float4 w2 = ((const float4*)(lw + 2*DDIM ))[j];
        const float4 w3 = ((const float4*)(lw + 3*DDIM ))[j];
        const float4 bb = ((const float4*)(lw + 4*DDIM ))[j];
        const float4 ow = ((const float4*)(lw + 5*DDIM ))[j];
        const float x0 = a.x * (c.x * fmaf(r.x, w1.x, w0.x) + u.x * fmaf(r.x, w3.x, w2.x)) + bb.x;
        const float x1 = a.y * (c.y * fmaf(r.y, w1.y, w0.y) + u.y * fmaf(r.y, w3.y, w2.y)) + bb.y;
        const float x2 = a.z * (c.z * fmaf(r.z, w1.z, w0.z) + u.z * fmaf(r.z, w3.z, w2.z)) + bb.z;
        const float x3 = a.w * (c.w * fmaf(r.w, w1.w, w0.w) + u.w * fmaf(r.w, w3.w, w2.w)) + bb.w;
        logit += fmaxf(x0, 0.f) * ow.x + fmaxf(x1, 0.f) * ow.y
               + fmaxf(x2, 0.f) * ow.z + fmaxf(x3, 0.f) * ow.w;
    }

    // segment softmax: the 8 edges of a segment sit in one aligned 8-lane group
    float m = logit;
    m = fmaxf(m, __shfl_xor(m, 1, 64));
    m = fmaxf(m, __shfl_xor(m, 2, 64));
    m = fmaxf(m, __shfl_xor(m, 4, 64));
    const float ex = expf(logit - m);
    float sd = ex;
    sd += __shfl_xor(sd, 1, 64);
    sd += __shfl_xor(sd, 2, 64);
    sd += __shfl_xor(sd, 4, 64);
    const float tr = ex / sd;

    const float na = node_attention[bc + h.y];           // segment-uniform
    const float ta = na * tr * edges_y[e];               // coalesced
    trans_attention[e] = ta;                             // coalesced
    atomicAdd(new_node_attention + bc + p.x, ta);
}

extern "C" void kernel_launch(void* const* d_in, const int* in_sizes, int n_in,
                              void* d_out, int out_size, void* d_ws, size_t ws_size,
                              hipStream_t stream) {
    const float* node_attention = (const float*)d_in[0];
    const float* hidden_con    = (const float*)d_in[1];
    const float* hidden_uncon  = (const float*)d_in[2];
    const float* edges_y       = (const float*)d_in[3];
    const float* rel_emb       = (const float*)d_in[4];
    const float* ws            = (const float*)d_in[5];
    const float* bvec          = (const float*)d_in[6];
    const float* out_w         = (const float*)d_in[7];
    const int*   edges         = (const int*)d_in[9];

    const long E       = in_sizes[9] / 6;     // 800000
    const int  BN      = in_sizes[0];         // 400000
    const int  N_nodes = in_sizes[2] / DDIM;  // 50000

    float* trans_attention    = (float*)d_out;
    float* new_node_attention = (float*)d_out + E;

    // d_out is poisoned 0xAA before every timed launch -> zero the scatter target.
    hipMemsetAsync(new_node_attention, 0, (size_t)BN * sizeof(float), stream);

    const int blocks = (int)((E + 255) / 256);   // 3125
    attn_flow_kernel<<<blocks, 256, 0, stream>>>(
        node_attention, hidden_con, hidden_uncon, edges_y, rel_emb,
        ws, bvec, out_w, edges,
        trans_attention, new_node_attention, E, N_nodes);
}

// Round 7
// 173.630 us; speedup vs baseline: 1.4643x; 1.4643x over previous
//
#include <hip/hip_runtime.h>

// AttentionFlow: B=8, N=50000, D=32, DEG=8, E=800000; segments = 8 consecutive edges.
//
// Layout: lane = k*8+q (k = edge-in-segment, q = dim quad) -> every gathered row
// is consumed as one full 128B line by 8 lanes (byte-efficient, round-1 style).
// MLP fix: gather rows via __builtin_amdgcn_global_load_lds (per-lane global
// source address, LDS dest = uniform base + lane*16). 12 staged gathers per wave
// (4 segments x {hc_vj, hu_vj, rel_emb}) issue back-to-back with NO destination
// VGPRs -> ~104 lines in flight per wave, bypassing the compiler's ~8-load
// clustering limit that capped rounds 1-4 at ~2 TB/s.
// out_b dropped (constant per segment, cancels in segment softmax).

#define DDIM 32
#define NSEG 4

#define GL2LDS(srcptr, dstptr)                                                    \
    __builtin_amdgcn_global_load_lds(                                             \
        (const __attribute__((address_space(1))) void*)(srcptr),                  \
        (__attribute__((address_space(3))) void*)(dstptr), 16, 0, 0)

__global__ __launch_bounds__(256) void attn_flow_kernel(
    const float* __restrict__ node_attention,   // B*N
    const float* __restrict__ hidden_con,       // B*N*D
    const float* __restrict__ hidden_uncon,     // N*D
    const float* __restrict__ edges_y,          // E
    const float* __restrict__ rel_emb,          // R*D
    const float* __restrict__ ws,               // 4*D
    const float* __restrict__ bvec,             // D
    const float* __restrict__ out_w,            // D
    const int*   __restrict__ edges,            // E*6 (idx,vi,vj,rel,idx_vi,key)
    float* __restrict__ trans_attention,        // E
    float* __restrict__ new_node_attention,     // B*N
    int n_groups, int N_nodes)
{
    // [wave][seg][op(c,u,r)][lane] float4 -> 4*4*3*64*16 = 48 KiB / block
    __shared__ float4 lds[4][NSEG][3][64];

    const int wid  = threadIdx.x >> 6;
    const int lane = threadIdx.x & 63;
    const int wave = (int)((blockIdx.x * 256u + threadIdx.x) >> 6);
    const int gid0 = wave * NSEG;                 // n_groups % 4 == 0, no tail
    if (gid0 >= n_groups) return;
    const int k = lane >> 3;   // edge within segment
    const int q = lane & 7;    // dim quad

    // ---- headers: (idx,vi) uniform per segment; (vj,rel) per edge k ----
    const int2 h0 = *(const int2*)(edges + (long)(gid0 + 0) * 48);
    const int2 h1 = *(const int2*)(edges + (long)(gid0 + 1) * 48);
    const int2 h2 = *(const int2*)(edges + (long)(gid0 + 2) * 48);
    const int2 h3 = *(const int2*)(edges + (long)(gid0 + 3) * 48);
    const int2 p0 = *(const int2*)(edges + ((long)(gid0 + 0) * 8 + k) * 6 + 2);
    const int2 p1 = *(const int2*)(edges + ((long)(gid0 + 1) * 8 + k) * 6 + 2);
    const int2 p2 = *(const int2*)(edges + ((long)(gid0 + 2) * 8 + k) * 6 + 2);
    const int2 p3 = *(const int2*)(edges + ((long)(gid0 + 3) * 8 + k) * 6 + 2);

    const long bc0 = (long)h0.x * N_nodes;
    const long bc1 = (long)h1.x * N_nodes;
    const long bc2 = (long)h2.x * N_nodes;
    const long bc3 = (long)h3.x * N_nodes;

    // ---- stage 12 gathers into LDS: no dest VGPRs, all in flight together ----
#define STAGE(s)                                                                   \
    GL2LDS(hidden_con  + (bc##s + p##s.x) * DDIM + q * 4, &lds[wid][s][0][0]);     \
    GL2LDS(hidden_uncon + (long)p##s.x   * DDIM + q * 4, &lds[wid][s][1][0]);      \
    GL2LDS(rel_emb     + (long)p##s.y   * DDIM + q * 4, &lds[wid][s][2][0]);
    STAGE(0) STAGE(1) STAGE(2) STAGE(3)
#undef STAGE

    // ---- regular loads that ride alongside the staged gathers ----
    const float4 a0 = ((const float4*)(hidden_con + (bc0 + h0.y) * DDIM))[q];
    const float4 a1 = ((const float4*)(hidden_con + (bc1 + h1.y) * DDIM))[q];
    const float4 a2 = ((const float4*)(hidden_con + (bc2 + h2.y) * DDIM))[q];
    const float4 a3 = ((const float4*)(hidden_con + (bc3 + h3.y) * DDIM))[q];
    const float na0 = node_attention[bc0 + h0.y];
    const float na1 = node_attention[bc1 + h1.y];
    const float na2 = node_attention[bc2 + h2.y];
    const float na3 = node_attention[bc3 + h3.y];
    const float ey0 = edges_y[(long)(gid0 + 0) * 8 + k];
    const float ey1 = edges_y[(long)(gid0 + 1) * 8 + k];
    const float ey2 = edges_y[(long)(gid0 + 2) * 8 + k];
    const float ey3 = edges_y[(long)(gid0 + 3) * 8 + k];

    // per-q weights (tiny, cache-resident)
    const float4 w0 = ((const float4*)(ws          ))[q];
    const float4 w1 = ((const float4*)(ws +   DDIM))[q];
    const float4 w2 = ((const float4*)(ws + 2*DDIM))[q];
    const float4 w3 = ((const float4*)(ws + 3*DDIM))[q];
    const float4 bb = ((const float4*)(bvec ))[q];
    const float4 ow = ((const float4*)(out_w))[q];

    // drain all staged gathers (and the register loads) before LDS readback
    asm volatile("s_waitcnt vmcnt(0)" ::: "memory");

    // ---- compute + epilogue per segment ----
#define COMP(s)                                                                    \
    {                                                                              \
        const float4 c = lds[wid][s][0][lane];                                     \
        const float4 u = lds[wid][s][1][lane];                                     \
        const float4 r = lds[wid][s][2][lane];                                     \
        float x0 = a##s.x * (c.x * fmaf(r.x, w1.x, w0.x)                           \
                           + u.x * fmaf(r.x, w3.x, w2.x)) + bb.x;                  \
        float x1 = a##s.y * (c.y * fmaf(r.y, w1.y, w0.y)                           \
                           + u.y * fmaf(r.y, w3.y, w2.y)) + bb.y;                  \
        float x2 = a##s.z * (c.z * fmaf(r.z, w1.z, w0.z)                           \
                           + u.z * fmaf(r.z, w3.z, w2.z)) + bb.z;                  \
        float x3 = a##s.w * (c.w * fmaf(r.w, w1.w, w0.w)                           \
                           + u.w * fmaf(r.w, w3.w, w2.w)) + bb.w;                  \
        float pp = fmaxf(x0, 0.f) * ow.x + fmaxf(x1, 0.f) * ow.y                   \
                 + fmaxf(x2, 0.f) * ow.z + fmaxf(x3, 0.f) * ow.w;                  \
        pp += __shfl_xor(pp, 1, 64);                                               \
        pp += __shfl_xor(pp, 2, 64);                                               \
        pp += __shfl_xor(pp, 4, 64);                                               \
        float mm = pp;                                                             \
        mm = fmaxf(mm, __shfl_xor(mm, 8, 64));                                     \
        mm = fmaxf(mm, __shfl_xor(mm, 16, 64));                                    \
        mm = fmaxf(mm, __shfl_xor(mm, 32, 64));                                    \
        const float ex = expf(pp - mm);                                            \
        float sd = ex;                                                             \
        sd += __shfl_xor(sd, 8, 64);                                               \
        sd += __shfl_xor(sd, 16, 64);                                              \
        sd += __shfl_xor(sd, 32, 64);                                              \
        const float tr = ex / sd;                                                  \
        if (q == 0) {                                                              \
            const long e = (long)(gid0 + s) * 8 + k;                               \
            const float ta = na##s * tr * ey##s;                                   \
            trans_attention[e] = ta;                                               \
            atomicAdd(new_node_attention + bc##s + p##s.x, ta);                    \
        }                                                                          \
    }
    COMP(0) COMP(1) COMP(2) COMP(3)
#undef COMP
}

extern "C" void kernel_launch(void* const* d_in, const int* in_sizes, int n_in,
                              void* d_out, int out_size, void* d_ws, size_t ws_size,
                              hipStream_t stream) {
    const float* node_attention = (const float*)d_in[0];
    const float* hidden_con    = (const float*)d_in[1];
    const float* hidden_uncon  = (const float*)d_in[2];
    const float* edges_y       = (const float*)d_in[3];
    const float* rel_emb       = (const float*)d_in[4];
    const float* ws            = (const float*)d_in[5];
    const float* bvec          = (const float*)d_in[6];
    const float* out_w         = (const float*)d_in[7];
    const int*   edges         = (const int*)d_in[9];

    const int E        = in_sizes[9] / 6;     // 800000
    const int BN       = in_sizes[0];         // 400000
    const int N_nodes  = in_sizes[2] / DDIM;  // 50000
    const int n_groups = E / 8;               // 100000

    float* trans_attention    = (float*)d_out;
    float* new_node_attention = (float*)d_out + E;

    // d_out is poisoned 0xAA before every timed launch -> zero the scatter target.
    hipMemsetAsync(new_node_attention, 0, (size_t)BN * sizeof(float), stream);

    const int n_waves = (n_groups + NSEG - 1) / NSEG;   // 25000
    const int blocks  = (n_waves + 3) / 4;              // 6250 (4 waves/block)
    attn_flow_kernel<<<blocks, 256, 0, stream>>>(
        node_attention, hidden_con, hidden_uncon, edges_y, rel_emb,
        ws, bvec, out_w, edges,
        trans_attention, new_node_attention, n_groups, N_nodes);
}

// Round 9
// 164.529 us; speedup vs baseline: 1.5453x; 1.0553x over previous
//
#include <hip/hip_runtime.h>

// AttentionFlow: B=8, N=50000, D=32, DEG=8, E=800000; segments = 8 consecutive edges.
//
// Layout: lane = k*8+q (k = edge-in-segment, q = dim quad) -> every gathered row
// is consumed as one full 128B line by 8 lanes.
// MLP via __builtin_amdgcn_global_load_lds (no destination VGPRs): 8 staged
// gathers per wave (4 segments x {hc_vj, hu_vj}) issue back-to-back.
// rel_emb (64 KB, cache-hot) is loaded via regular float4 -> LDS/block drops
// 48->32 KB -> 5 blocks/CU (20 waves, 62%) instead of 3 (30%). This is the
// first config with BOTH high occupancy AND high per-wave lines-in-flight.
// out_b dropped (constant per segment, cancels in segment softmax).

#define DDIM 32
#define NSEG 4

#define GL2LDS(srcptr, dstptr)                                                    \
    __builtin_amdgcn_global_load_lds(                                             \
        (const __attribute__((address_space(1))) void*)(srcptr),                  \
        (__attribute__((address_space(3))) void*)(dstptr), 16, 0, 0)

__global__ __launch_bounds__(256, 5) void attn_flow_kernel(
    const float* __restrict__ node_attention,   // B*N
    const float* __restrict__ hidden_con,       // B*N*D
    const float* __restrict__ hidden_uncon,     // N*D
    const float* __restrict__ edges_y,          // E
    const float* __restrict__ rel_emb,          // R*D
    const float* __restrict__ ws,               // 4*D
    const float* __restrict__ bvec,             // D
    const float* __restrict__ out_w,            // D
    const int*   __restrict__ edges,            // E*6 (idx,vi,vj,rel,idx_vi,key)
    float* __restrict__ trans_attention,        // E
    float* __restrict__ new_node_attention,     // B*N
    int n_groups, int N_nodes)
{
    // [wave][seg][op(c,u)][lane] float4 -> 4*4*2*64*16 = 32 KiB / block
    __shared__ float4 lds[4][NSEG][2][64];

    const int wid  = threadIdx.x >> 6;
    const int lane = threadIdx.x & 63;
    const int wave = (int)((blockIdx.x * 256u + threadIdx.x) >> 6);
    const int gid0 = wave * NSEG;                 // n_groups % 4 == 0, no tail
    if (gid0 >= n_groups) return;
    const int k = lane >> 3;   // edge within segment
    const int q = lane & 7;    // dim quad

    // ---- headers: (idx,vi) uniform per segment; (vj,rel) per edge k ----
    const int2 h0 = *(const int2*)(edges + (long)(gid0 + 0) * 48);
    const int2 h1 = *(const int2*)(edges + (long)(gid0 + 1) * 48);
    const int2 h2 = *(const int2*)(edges + (long)(gid0 + 2) * 48);
    const int2 h3 = *(const int2*)(edges + (long)(gid0 + 3) * 48);
    const int2 p0 = *(const int2*)(edges + ((long)(gid0 + 0) * 8 + k) * 6 + 2);
    const int2 p1 = *(const int2*)(edges + ((long)(gid0 + 1) * 8 + k) * 6 + 2);
    const int2 p2 = *(const int2*)(edges + ((long)(gid0 + 2) * 8 + k) * 6 + 2);
    const int2 p3 = *(const int2*)(edges + ((long)(gid0 + 3) * 8 + k) * 6 + 2);

    const long bc0 = (long)h0.x * N_nodes;
    const long bc1 = (long)h1.x * N_nodes;
    const long bc2 = (long)h2.x * N_nodes;
    const long bc3 = (long)h3.x * N_nodes;

    // ---- stage 8 gathers into LDS: no dest VGPRs, all in flight together ----
#define STAGE(s)                                                                   \
    GL2LDS(hidden_con  + (bc##s + p##s.x) * DDIM + q * 4, &lds[wid][s][0][0]);     \
    GL2LDS(hidden_uncon + (long)p##s.x   * DDIM + q * 4, &lds[wid][s][1][0]);
    STAGE(0) STAGE(1) STAGE(2) STAGE(3)
#undef STAGE

    // ---- register loads riding alongside the staged gathers ----
    const float4 r0 = ((const float4*)(rel_emb + (long)p0.y * DDIM))[q];
    const float4 r1 = ((const float4*)(rel_emb + (long)p1.y * DDIM))[q];
    const float4 r2 = ((const float4*)(rel_emb + (long)p2.y * DDIM))[q];
    const float4 r3 = ((const float4*)(rel_emb + (long)p3.y * DDIM))[q];
    const float4 a0 = ((const float4*)(hidden_con + (bc0 + h0.y) * DDIM))[q];
    const float4 a1 = ((const float4*)(hidden_con + (bc1 + h1.y) * DDIM))[q];
    const float4 a2 = ((const float4*)(hidden_con + (bc2 + h2.y) * DDIM))[q];
    const float4 a3 = ((const float4*)(hidden_con + (bc3 + h3.y) * DDIM))[q];
    const float na0 = node_attention[bc0 + h0.y];
    const float na1 = node_attention[bc1 + h1.y];
    const float na2 = node_attention[bc2 + h2.y];
    const float na3 = node_attention[bc3 + h3.y];
    const float ey0 = edges_y[(long)(gid0 + 0) * 8 + k];
    const float ey1 = edges_y[(long)(gid0 + 1) * 8 + k];
    const float ey2 = edges_y[(long)(gid0 + 2) * 8 + k];
    const float ey3 = edges_y[(long)(gid0 + 3) * 8 + k];

    // per-q weights (tiny, cache-resident)
    const float4 w0 = ((const float4*)(ws          ))[q];
    const float4 w1 = ((const float4*)(ws +   DDIM))[q];
    const float4 w2 = ((const float4*)(ws + 2*DDIM))[q];
    const float4 w3 = ((const float4*)(ws + 3*DDIM))[q];
    const float4 bb = ((const float4*)(bvec ))[q];
    const float4 ow = ((const float4*)(out_w))[q];

    // drain staged gathers (and register loads) before LDS readback
    asm volatile("s_waitcnt vmcnt(0)" ::: "memory");

    // ---- compute + epilogue per segment ----
#define COMP(s)                                                                    \
    {                                                                              \
        const float4 c = lds[wid][s][0][lane];                                     \
        const float4 u = lds[wid][s][1][lane];                                     \
        float x0 = a##s.x * (c.x * fmaf(r##s.x, w1.x, w0.x)                        \
                           + u.x * fmaf(r##s.x, w3.x, w2.x)) + bb.x;               \
        float x1 = a##s.y * (c.y * fmaf(r##s.y, w1.y, w0.y)                        \
                           + u.y * fmaf(r##s.y, w3.y, w2.y)) + bb.y;               \
        float x2 = a##s.z * (c.z * fmaf(r##s.z, w1.z, w0.z)                        \
                           + u.z * fmaf(r##s.z, w3.z, w2.z)) + bb.z;               \
        float x3 = a##s.w * (c.w * fmaf(r##s.w, w1.w, w0.w)                        \
                           + u.w * fmaf(r##s.w, w3.w, w2.w)) + bb.w;               \
        float pp = fmaxf(x0, 0.f) * ow.x + fmaxf(x1, 0.f) * ow.y                   \
                 + fmaxf(x2, 0.f) * ow.z + fmaxf(x3, 0.f) * ow.w;                  \
        pp += __shfl_xor(pp, 1, 64);                                               \
        pp += __shfl_xor(pp, 2, 64);                                               \
        pp += __shfl_xor(pp, 4, 64);                                               \
        float mm = pp;                                                             \
        mm = fmaxf(mm, __shfl_xor(mm, 8, 64));                                     \
        mm = fmaxf(mm, __shfl_xor(mm, 16, 64));                                    \
        mm = fmaxf(mm, __shfl_xor(mm, 32, 64));                                    \
        const float ex = expf(pp - mm);                                            \
        float sd = ex;                                                             \
        sd += __shfl_xor(sd, 8, 64);                                               \
        sd += __shfl_xor(sd, 16, 64);                                              \
        sd += __shfl_xor(sd, 32, 64);                                              \
        const float tr = ex / sd;                                                  \
        if (q == 0) {                                                              \
            const long e = (long)(gid0 + s) * 8 + k;                               \
            const float ta = na##s * tr * ey##s;                                   \
            trans_attention[e] = ta;                                               \
            atomicAdd(new_node_attention + bc##s + p##s.x, ta);                    \
        }                                                                          \
    }
    COMP(0) COMP(1) COMP(2) COMP(3)
#undef COMP
}

extern "C" void kernel_launch(void* const* d_in, const int* in_sizes, int n_in,
                              void* d_out, int out_size, void* d_ws, size_t ws_size,
                              hipStream_t stream) {
    const float* node_attention = (const float*)d_in[0];
    const float* hidden_con    = (const float*)d_in[1];
    const float* hidden_uncon  = (const float*)d_in[2];
    const float* edges_y       = (const float*)d_in[3];
    const float* rel_emb       = (const float*)d_in[4];
    const float* ws            = (const float*)d_in[5];
    const float* bvec          = (const float*)d_in[6];
    const float* out_w         = (const float*)d_in[7];
    const int*   edges         = (const int*)d_in[9];

    const int E        = in_sizes[9] / 6;     // 800000
    const int BN       = in_sizes[0];         // 400000
    const int N_nodes  = in_sizes[2] / DDIM;  // 50000
    const int n_groups = E / 8;               // 100000

    float* trans_attention    = (float*)d_out;
    float* new_node_attention = (float*)d_out + E;

    // d_out is poisoned 0xAA before every timed launch -> zero the scatter target.
    hipMemsetAsync(new_node_attention, 0, (size_t)BN * sizeof(float), stream);

    const int n_waves = (n_groups + NSEG - 1) / NSEG;   // 25000
    const int blocks  = (n_waves + 3) / 4;              // 6250 (4 waves/block)
    attn_flow_kernel<<<blocks, 256, 0, stream>>>(
        node_attention, hidden_con, hidden_uncon, edges_y, rel_emb,
        ws, bvec, out_w, edges,
        trans_attention, new_node_attention, n_groups, N_nodes);
}

// Round 12
// 163.617 us; speedup vs baseline: 1.5540x; 1.0056x over previous
//
#include <hip/hip_runtime.h>

// AttentionFlow: B=8, N=50000, D=32, DEG=8, E=800000; segments = 8 consecutive edges.
//
// Layout: lane = k*8+q (k = edge-in-segment, q = dim quad) -> every gathered row
// is consumed as one full 128B line by 8 lanes.
// MLP via __builtin_amdgcn_global_load_lds (no destination VGPRs): 4 staged
// gathers per wave (2 segments x {hc_vj, hu_vj}).
// NSEG=2 -> LDS 16 KB/block -> 8+ blocks/CU -> up to 32 waves/CU (HW cap).
// Round-9 A/B isolator: occupancy 37% -> ~2x, per-wave staged lines halved.
// out_b dropped (constant per segment, cancels in segment softmax).

#define DDIM 32
#define NSEG 2

#define GL2LDS(srcptr, dstptr)                                                    \
    __builtin_amdgcn_global_load_lds(                                             \
        (const __attribute__((address_space(1))) void*)(srcptr),                  \
        (__attribute__((address_space(3))) void*)(dstptr), 16, 0, 0)

__global__ __launch_bounds__(256, 8) void attn_flow_kernel(
    const float* __restrict__ node_attention,   // B*N
    const float* __restrict__ hidden_con,       // B*N*D
    const float* __restrict__ hidden_uncon,     // N*D
    const float* __restrict__ edges_y,          // E
    const float* __restrict__ rel_emb,          // R*D
    const float* __restrict__ ws,               // 4*D
    const float* __restrict__ bvec,             // D
    const float* __restrict__ out_w,            // D
    const int*   __restrict__ edges,            // E*6 (idx,vi,vj,rel,idx_vi,key)
    float* __restrict__ trans_attention,        // E
    float* __restrict__ new_node_attention,     // B*N
    int n_groups, int N_nodes)
{
    // [wave][seg][op(c,u)][lane] float4 -> 4*2*2*64*16 = 16 KiB / block
    __shared__ float4 lds[4][NSEG][2][64];

    const int wid  = threadIdx.x >> 6;
    const int lane = threadIdx.x & 63;
    const int wave = (int)((blockIdx.x * 256u + threadIdx.x) >> 6);
    const int gid0 = wave * NSEG;                 // n_groups % 2 == 0, no tail
    if (gid0 >= n_groups) return;
    const int k = lane >> 3;   // edge within segment
    const int q = lane & 7;    // dim quad

    // ---- headers: (idx,vi) uniform per segment; (vj,rel) per edge k ----
    const int2 h0 = *(const int2*)(edges + (long)(gid0 + 0) * 48);
    const int2 h1 = *(const int2*)(edges + (long)(gid0 + 1) * 48);
    const int2 p0 = *(const int2*)(edges + ((long)(gid0 + 0) * 8 + k) * 6 + 2);
    const int2 p1 = *(const int2*)(edges + ((long)(gid0 + 1) * 8 + k) * 6 + 2);

    const long bc0 = (long)h0.x * N_nodes;
    const long bc1 = (long)h1.x * N_nodes;

    // ---- stage 4 gathers into LDS: no dest VGPRs, all in flight together ----
#define STAGE(s)                                                                   \
    GL2LDS(hidden_con  + (bc##s + p##s.x) * DDIM + q * 4, &lds[wid][s][0][0]);     \
    GL2LDS(hidden_uncon + (long)p##s.x   * DDIM + q * 4, &lds[wid][s][1][0]);
    STAGE(0) STAGE(1)
#undef STAGE

    // ---- register loads riding alongside the staged gathers ----
    const float4 r0 = ((const float4*)(rel_emb + (long)p0.y * DDIM))[q];
    const float4 r1 = ((const float4*)(rel_emb + (long)p1.y * DDIM))[q];
    const float4 a0 = ((const float4*)(hidden_con + (bc0 + h0.y) * DDIM))[q];
    const float4 a1 = ((const float4*)(hidden_con + (bc1 + h1.y) * DDIM))[q];
    const float na0 = node_attention[bc0 + h0.y];
    const float na1 = node_attention[bc1 + h1.y];
    const float ey0 = edges_y[(long)(gid0 + 0) * 8 + k];
    const float ey1 = edges_y[(long)(gid0 + 1) * 8 + k];

    // per-q weights (tiny, cache-resident)
    const float4 w0 = ((const float4*)(ws          ))[q];
    const float4 w1 = ((const float4*)(ws +   DDIM))[q];
    const float4 w2 = ((const float4*)(ws + 2*DDIM))[q];
    const float4 w3 = ((const float4*)(ws + 3*DDIM))[q];
    const float4 bb = ((const float4*)(bvec ))[q];
    const float4 ow = ((const float4*)(out_w))[q];

    // drain staged gathers (and register loads) before LDS readback
    asm volatile("s_waitcnt vmcnt(0)" ::: "memory");

    // ---- compute + epilogue per segment ----
#define COMP(s)                                                                    \
    {                                                                              \
        const float4 c = lds[wid][s][0][lane];                                     \
        const float4 u = lds[wid][s][1][lane];                                     \
        float x0 = a##s.x * (c.x * fmaf(r##s.x, w1.x, w0.x)                        \
                           + u.x * fmaf(r##s.x, w3.x, w2.x)) + bb.x;               \
        float x1 = a##s.y * (c.y * fmaf(r##s.y, w1.y, w0.y)                        \
                           + u.y * fmaf(r##s.y, w3.y, w2.y)) + bb.y;               \
        float x2 = a##s.z * (c.z * fmaf(r##s.z, w1.z, w0.z)                        \
                           + u.z * fmaf(r##s.z, w3.z, w2.z)) + bb.z;               \
        float x3 = a##s.w * (c.w * fmaf(r##s.w, w1.w, w0.w)                        \
                           + u.w * fmaf(r##s.w, w3.w, w2.w)) + bb.w;               \
        float pp = fmaxf(x0, 0.f) * ow.x + fmaxf(x1, 0.f) * ow.y                   \
                 + fmaxf(x2, 0.f) * ow.z + fmaxf(x3, 0.f) * ow.w;                  \
        pp += __shfl_xor(pp, 1, 64);                                               \
        pp += __shfl_xor(pp, 2, 64);                                               \
        pp += __shfl_xor(pp, 4, 64);                                               \
        float mm = pp;                                                             \
        mm = fmaxf(mm, __shfl_xor(mm, 8, 64));                                     \
        mm = fmaxf(mm, __shfl_xor(mm, 16, 64));                                    \
        mm = fmaxf(mm, __shfl_xor(mm, 32, 64));                                    \
        const float ex = expf(pp - mm);                                            \
        float sd = ex;                                                             \
        sd += __shfl_xor(sd, 8, 64);                                               \
        sd += __shfl_xor(sd, 16, 64);                                              \
        sd += __shfl_xor(sd, 32, 64);                                              \
        const float tr = ex / sd;                                                  \
        if (q == 0) {                                                              \
            const long e = (long)(gid0 + s) * 8 + k;                               \
            const float ta = na##s * tr * ey##s;                                   \
            trans_attention[e] = ta;                                               \
            atomicAdd(new_node_attention + bc##s + p##s.x, ta);                    \
        }                                                                          \
    }
    COMP(0) COMP(1)
#undef COMP
}

extern "C" void kernel_launch(void* const* d_in, const int* in_sizes, int n_in,
                              void* d_out, int out_size, void* d_ws, size_t ws_size,
                              hipStream_t stream) {
    const float* node_attention = (const float*)d_in[0];
    const float* hidden_con    = (const float*)d_in[1];
    const float* hidden_uncon  = (const float*)d_in[2];
    const float* edges_y       = (const float*)d_in[3];
    const float* rel_emb       = (const float*)d_in[4];
    const float* ws            = (const float*)d_in[5];
    const float* bvec          = (const float*)d_in[6];
    const float* out_w         = (const float*)d_in[7];
    const int*   edges         = (const int*)d_in[9];

    const int E        = in_sizes[9] / 6;     // 800000
    const int BN       = in_sizes[0];         // 400000
    const int N_nodes  = in_sizes[2] / DDIM;  // 50000
    const int n_groups = E / 8;               // 100000

    float* trans_attention    = (float*)d_out;
    float* new_node_attention = (float*)d_out + E;

    // d_out is poisoned 0xAA before every timed launch -> zero the scatter target.
    hipMemsetAsync(new_node_attention, 0, (size_t)BN * sizeof(float), stream);

    const int n_waves = (n_groups + NSEG - 1) / NSEG;   // 50000
    const int blocks  = (n_waves + 3) / 4;              // 12500 (4 waves/block)
    attn_flow_kernel<<<blocks, 256, 0, stream>>>(
        node_attention, hidden_con, hidden_uncon, edges_y, rel_emb,
        ws, bvec, out_w, edges,
        trans_attention, new_node_attention, n_groups, N_nodes);
}